// Round 8
// baseline (89.597 us; speedup 1.0000x reference)
//
#include <hip/hip_runtime.h>
#include <hip/hip_bf16.h>
#include <stdint.h>

constexpr int NUM_NODES = 120000;
constexpr int Tn = 10;
constexpr int Bb = 64, Rr = 4, Nn = 64, Cc = 64, Ii = 64;
constexpr int RSTR  = 147456;   // per-relation Wf stride (bf16 elems)
constexpr int OFF0  = 0;        // L0 w1   [tap2][ct4][ks4][lane64][8]
constexpr int OFF1  = 16384;    // L0 down [ct4][ks4][lane64][8]
constexpr int OFF2  = 24576;    // L0 w2   [tap2][ct4][ks2][lane64][8]
constexpr int OFFL0 = 32768;    // levels  14 x [tap2][ct4][ks2][lane64][8]

// LDS byte offsets. X (160 cols x 256B) dead after pass2; H-chain aliases it.
constexpr int OFF_X  = 0;        // 40960
constexpr int OFF_H0 = 0;        // 5 slots  (10240)
constexpr int OFF_H1 = 10240;    // 3 slots  (6144)
constexpr int OFF_H2 = 16384;    // 2 slots  (4096)
constexpr int OFF_H3 = 20480;    // 1 slot   (2048); H4/H5/H6 follow at +2048 each
constexpr int OFF_Y  = 40960;    // up to 10 slots (20480)
constexpr int ZOFF   = 61440;    // 256B zero block
constexpr int SMEMB  = 61696;

typedef __attribute__((ext_vector_type(8))) short bf16x8;
typedef __attribute__((ext_vector_type(4))) float f32x4;
typedef __attribute__((ext_vector_type(4))) short s16x4;

__device__ __forceinline__ short f2bf(float f) {
  __hip_bfloat16 h = __float2bfloat16(f);
  return *reinterpret_cast<short*>(&h);
}
__device__ __forceinline__ float bf2f(short s) {
  union { unsigned int u; float f; } x;
  x.u = ((unsigned int)(unsigned short)s) << 16;
  return x.f;
}

// ---------------------------------------------------------------------------
// Bake weights into per-lane MFMA A-fragments (bf16), and zero P + counters.
// ---------------------------------------------------------------------------
extern "C" __global__ void prep_kernel(const float* __restrict__ w1_0,
                                       const float* __restrict__ w2_0,
                                       const float* __restrict__ down_w,
                                       const float* __restrict__ w1s,
                                       const float* __restrict__ w2s,
                                       short* __restrict__ Wf,
                                       float* __restrict__ P,
                                       int* __restrict__ cnt) {
  int i0 = blockIdx.x * blockDim.x + threadIdx.x;
  int stride = gridDim.x * blockDim.x;
  // zero P (65536 f32) and counters (64 int)
  for (int z = i0; z < 65536 + 64; z += stride) {
    if (z < 65536) P[z] = 0.f;
    else cnt[z - 65536] = 0;
  }
  for (int e = i0; e < Rr * RSTR; e += stride) {
    int r = e / RSTR, q = e - r * RSTR;
    float v;
    if (q < 16384) {
      int j = q & 7, lane = (q >> 3) & 63, ks = (q >> 9) & 3, ct = (q >> 11) & 3, tap = (q >> 13) & 1;
      int cout = ct * 16 + (lane & 15), cin = ks * 32 + (lane >> 4) * 8 + j;
      v = w1_0[((r * 64 + cout) * 128 + cin) * 2 + tap];
    } else if (q < 24576) {
      int q2 = q - 16384;
      int j = q2 & 7, lane = (q2 >> 3) & 63, ks = (q2 >> 9) & 3, ct = (q2 >> 11) & 3;
      int cout = ct * 16 + (lane & 15), cin = ks * 32 + (lane >> 4) * 8 + j;
      v = down_w[(r * 64 + cout) * 128 + cin];
    } else if (q < 32768) {
      int q2 = q - 24576;
      int j = q2 & 7, lane = (q2 >> 3) & 63, ks = (q2 >> 9) & 1, ct = (q2 >> 10) & 3, tap = (q2 >> 12) & 1;
      int cout = ct * 16 + (lane & 15), cin = ks * 32 + (lane >> 4) * 8 + j;
      v = w2_0[((r * 64 + cout) * 64 + cin) * 2 + tap];
    } else {
      int q2 = q - 32768;
      int lc = q2 >> 13;
      int l = lc >> 1, jw = lc & 1;
      int q3 = q2 & 8191;
      int j = q3 & 7, lane = (q3 >> 3) & 63, ks = (q3 >> 9) & 1, ct = (q3 >> 10) & 3, tap = (q3 >> 12) & 1;
      int cout = ct * 16 + (lane & 15), cin = ks * 32 + (lane >> 4) * 8 + j;
      const float* src = jw ? w2s : w1s;
      v = src[(((r * 7 + l) * 64 + cout) * 64 + cin) * 2 + tap];
    }
    Wf[e] = f2bf(v);
  }
}

// ---------------------------------------------------------------------------
// Sparse-slot conv pass. col = slot*16 + seq (16 seqs); tile == slot.
// ---------------------------------------------------------------------------
template <int KSN, int NMT, int NTAP, int ROWB>
__device__ __forceinline__ void conv_sp(const char* __restrict__ sm, int srcOff,
                                        const short* __restrict__ wf1,
                                        const short* __restrict__ wf0,
                                        const float* __restrict__ bias,
                                        const int (&T1)[NMT], const int (&T0)[NMT],
                                        int lane, int ct, f32x4 (&acc)[NMT]) {
  const int c16 = (lane >> 4) * 16;
  const int sw = (lane & 7) << 4;
  const int cm = lane & 15;
  float bv[4];
#pragma unroll
  for (int g = 0; g < 4; ++g) bv[g] = bias[ct * 16 + (lane >> 4) * 4 + g];
#pragma unroll
  for (int mt = 0; mt < NMT; ++mt) acc[mt] = (f32x4){bv[0], bv[1], bv[2], bv[3]};
  bf16x8 af1[KSN], af0[KSN];
#pragma unroll
  for (int ks = 0; ks < KSN; ++ks)
    af1[ks] = *(const bf16x8*)(wf1 + ((ct * KSN + ks) * 64 + lane) * 8);
  if (NTAP == 2) {
#pragma unroll
    for (int ks = 0; ks < KSN; ++ks)
      af0[ks] = *(const bf16x8*)(wf0 + ((ct * KSN + ks) * 64 + lane) * 8);
  }
#pragma unroll
  for (int mt = 0; mt < NMT; ++mt) {
    int s1 = T1[mt];
    const char* p1 = sm + ((s1 < 0) ? ZOFF : srcOff + (s1 * 16 + cm) * ROWB);
#pragma unroll
    for (int ks = 0; ks < KSN; ++ks) {
      bf16x8 b = *(const bf16x8*)(p1 + ((ks * 64 + c16) ^ sw));
      acc[mt] = __builtin_amdgcn_mfma_f32_16x16x32_bf16(af1[ks], b, acc[mt], 0, 0, 0);
    }
    if (NTAP == 2) {
      int s0 = T0[mt];
      const char* p0 = sm + ((s0 < 0) ? ZOFF : srcOff + (s0 * 16 + cm) * ROWB);
#pragma unroll
      for (int ks = 0; ks < KSN; ++ks) {
        bf16x8 b = *(const bf16x8*)(p0 + ((ks * 64 + c16) ^ sw));
        acc[mt] = __builtin_amdgcn_mfma_f32_16x16x32_bf16(af0[ks], b, acc[mt], 0, 0, 0);
      }
    }
  }
}

template <int NMT>
__device__ __forceinline__ void store_sp(char* __restrict__ sm, int dstOff, int s0,
                                         int lane, int ct, const f32x4 (&v)[NMT]) {
  const int co = ct * 32 + (lane >> 4) * 8;
  const int sw = (lane & 7) << 4;
#pragma unroll
  for (int mt = 0; mt < NMT; ++mt) {
    int oc = (s0 + mt) * 16 + (lane & 15);
    s16x4 p;
#pragma unroll
    for (int g = 0; g < 4; ++g) p[g] = f2bf(v[mt][g]);
    *(s16x4*)(sm + dstOff + oc * 128 + (co ^ sw)) = p;
  }
}

#define RELU_ALL(A, N)                                        \
  _Pragma("unroll") for (int _t = 0; _t < N; ++_t)            \
      _Pragma("unroll") for (int _g = 0; _g < 4; ++_g)        \
          A[_t][_g] = fmaxf(A[_t][_g], 0.f);

template <int NMT>
__device__ __forceinline__ void resid_sp(const char* __restrict__ sm, int prevOff,
                                         const int (&R)[NMT], int lane, int ct,
                                         f32x4 (&a)[NMT]) {
  const int co = ct * 32 + (lane >> 4) * 8;
  const int sw = (lane & 7) << 4;
  const int cm = lane & 15;
#pragma unroll
  for (int mt = 0; mt < NMT; ++mt) {
    const char* p = sm + prevOff + (R[mt] * 16 + cm) * 128;
    s16x4 q = *(const s16x4*)(p + (co ^ sw));
#pragma unroll
    for (int g = 0; g < 4; ++g)
      a[mt][g] = fmaxf(fmaxf(a[mt][g], 0.f) + bf2f(q[g]), 0.f);
  }
}

// Signal arrival for batch b; the 16th arriver reduces batch b and writes out.
// Call context: tid may span all waves; only wave 0 (tid<64) participates.
__device__ __forceinline__ void finalize(int b, const float* __restrict__ P,
                                         const float* __restrict__ rel_w,
                                         float* __restrict__ out,
                                         int* __restrict__ cnt, char* sm, int tid) {
  int ret = 0;
  if (tid == 0)
    ret = __hip_atomic_fetch_add(&cnt[b], 1, __ATOMIC_ACQ_REL, __HIP_MEMORY_SCOPE_AGENT);
  if (tid >= 64) return;
  ret = __shfl(ret, 0);
  if (ret != 15) return;
  float* Sl = (float*)sm;
  for (int idx = tid; idx < 256; idx += 64) {
    int rr = idx >> 6, cc = idx & 63;
    float s = 0.f;
#pragma unroll
    for (int p = 0; p < 4; ++p)
      s += __hip_atomic_load(&P[((rr * Bb + b) * 4 + p) * 64 + cc],
                             __ATOMIC_RELAXED, __HIP_MEMORY_SCOPE_AGENT);
    Sl[idx] = s;
  }
  float acc = 0.f;
  for (int rr = 0; rr < Rr; ++rr)
#pragma unroll
    for (int cc = 0; cc < 64; ++cc)
      acc += Sl[rr * 64 + cc] * rel_w[(rr * 64 + cc) * Ii + tid];
  out[b * Ii + tid] = acc;
}

// ---------------------------------------------------------------------------
// Main: 16 valid seqs per block, 512 thr = 8 waves (4 cout-tiles x 2 halves).
// Grid = r(4) x b(64) x chunk(4) = 1024 blocks. Reduce fused via counters.
// ---------------------------------------------------------------------------
extern "C" __global__ void __launch_bounds__(512, 4)
tcn_mfma(const float* __restrict__ emb, const int* __restrict__ align_,
         const int* __restrict__ nidx, const int* __restrict__ nmask,
         const float* __restrict__ b1_0, const float* __restrict__ b2_0,
         const float* __restrict__ down_b, const float* __restrict__ b1s,
         const float* __restrict__ b2s, const short* __restrict__ Wf,
         float* __restrict__ P, int* __restrict__ cnt,
         const float* __restrict__ rel_w, float* __restrict__ out) {
  __shared__ char sm[SMEMB];
  __shared__ int rowid[160];
  __shared__ float mkv[16];
  __shared__ int mapg[16];
  __shared__ int totv;

  const int tid = threadIdx.x;
  const int lane = tid & 63, wave = tid >> 6;
  const int ct = wave & 3, half = wave >> 2;
  const int blk = blockIdx.x;
  const int r = blk >> 8;
  const int b = (blk >> 2) & 63, chunk = blk & 3;

  // ---- ballot compaction (wave 0) ----
  if (tid < 64) {
    int n = tid;
    int msk = nmask[(b * Rr + r) * Nn + n];
    unsigned long long bal = __ballot(msk != 0);
    if (tid < 16) mapg[tid] = -1;
    if (tid == 0) totv = (int)__popcll(bal);
    int rank = (int)__popcll(bal & ((1ull << n) - 1ull));
    if (msk != 0 && rank >= chunk * 16 && rank < chunk * 16 + 16)
      mapg[rank - chunk * 16] = n;
  }
  if (tid >= 448 && tid < 480) *(uint64_t*)(sm + ZOFF + (tid - 448) * 8) = 0;
  __syncthreads();
  if (chunk * 16 >= totv) {   // inactive: P slice already zero; signal + exit
    finalize(b, P, rel_w, out, cnt, sm, tid);
    return;
  }

  // col = t*16 + seq
  if (tid < 160) {
    int t = tid >> 4, seq = tid & 15;
    int n2 = mapg[seq];
    int s = -1;
    if (n2 >= 0) {
      int ent = nidx[(b * Rr + r) * Nn + n2];
      s = align_[ent * Tn + t];
    }
    rowid[tid] = (n2 >= 0 && s >= 0) ? s : -1;
    if (t == 0) mkv[seq] = (n2 >= 0) ? 1.0f : 0.0f;
  }
  __syncthreads();

  // gather: 160 cols x 128 d, f32 -> bf16, swizzled LDS write
#pragma unroll
  for (int it = 0; it < 10; ++it) {
    int idx = tid + it * 512;
    int col = idx >> 5, d4 = idx & 31;
    int row = rowid[col];
    int t = col >> 4;
    s16x4 p = {0, 0, 0, 0};
    if (row >= 0) {
      const float4 v = *(const float4*)(emb + ((size_t)t * NUM_NODES + row) * 128 + d4 * 4);
      p[0] = f2bf(v.x); p[1] = f2bf(v.y); p[2] = f2bf(v.z); p[3] = f2bf(v.w);
    }
    *(s16x4*)(sm + OFF_X + col * 256 + ((d4 * 8) ^ ((col & 7) << 4))) = p;
  }
  __syncthreads();

  const short* wr = Wf + r * RSTR;

  // ---- pass1: Y0 = relu(conv1_0(X)), 10 slots ----
  {
    static constexpr int T1a[5] = {0, 1, 2, 3, 4}, T0a[5] = {-1, 0, 1, 2, 3};
    static constexpr int T1b[5] = {5, 6, 7, 8, 9}, T0b[5] = {4, 5, 6, 7, 8};
    f32x4 a[5];
    conv_sp<4, 5, 2, 256>(sm, OFF_X, wr + OFF0 + 8192, wr + OFF0, b1_0 + r * 64,
                          half ? T1b : T1a, half ? T0b : T0a, lane, ct, a);
    RELU_ALL(a, 5)
    store_sp<5>(sm, OFF_Y, half ? 5 : 0, lane, ct, a);
  }
  // ---- pass2: down(X) at odd t {1,3,5}/{5,7,9}, regs ----
  f32x4 accD[3];
  {
    static constexpr int TDa[3] = {1, 3, 5}, TDb[3] = {5, 7, 9};
    conv_sp<4, 3, 1, 256>(sm, OFF_X, wr + OFF1, wr + OFF1, down_b + r * 64,
                          half ? TDb : TDa, half ? TDb : TDa, lane, ct, accD);
  }
  __syncthreads();
  // ---- pass3: H0 = relu(relu(conv2_0(Y0)) + down), slots t={1,3,5,7,9} ----
  {
    static constexpr int T1a[3] = {1, 3, 5}, T0a[3] = {0, 2, 4};
    static constexpr int T1b[3] = {5, 7, 9}, T0b[3] = {4, 6, 8};
    f32x4 a[3];
    conv_sp<2, 3, 2, 128>(sm, OFF_Y, wr + OFF2 + 4096, wr + OFF2, b2_0 + r * 64,
                          half ? T1b : T1a, half ? T0b : T0a, lane, ct, a);
#pragma unroll
    for (int mt = 0; mt < 3; ++mt)
#pragma unroll
      for (int g = 0; g < 4; ++g)
        a[mt][g] = fmaxf(fmaxf(a[mt][g], 0.f) + accD[mt][g], 0.f);
    store_sp<3>(sm, OFF_H0, half ? 2 : 0, lane, ct, a);
  }
  __syncthreads();
  // ---- L1a (d=2): Y at H0 slots {0..4} ----
  {
    static constexpr int T1a[3] = {0, 1, 2}, T0a[3] = {-1, 0, 1};
    static constexpr int T1b[3] = {2, 3, 4}, T0b[3] = {1, 2, 3};
    const short* wl = wr + OFFL0;
    f32x4 a[3];
    conv_sp<2, 3, 2, 128>(sm, OFF_H0, wl + 4096, wl, b1s + (r * 7 + 0) * 64,
                          half ? T1b : T1a, half ? T0b : T0a, lane, ct, a);
    RELU_ALL(a, 3)
    store_sp<3>(sm, OFF_Y, half ? 2 : 0, lane, ct, a);
  }
  __syncthreads();
  // ---- L1b: H1 at t={1,5,9} ----
  {
    static constexpr int T1a[2] = {0, 2}, T0a[2] = {-1, 1}, Ra[2] = {0, 2};
    static constexpr int T1b[2] = {2, 4}, T0b[2] = {1, 3}, Rb[2] = {2, 4};
    const short* wl = wr + OFFL0 + 8192;
    f32x4 a[2];
    conv_sp<2, 2, 2, 128>(sm, OFF_Y, wl + 4096, wl, b2s + (r * 7 + 0) * 64,
                          half ? T1b : T1a, half ? T0b : T0a, lane, ct, a);
    resid_sp<2>(sm, OFF_H0, half ? Rb : Ra, lane, ct, a);
    store_sp<2>(sm, OFF_H1, half ? 1 : 0, lane, ct, a);
  }
  __syncthreads();
  // ---- L2a (d=4): Y at t={1,5,9} ----
  {
    static constexpr int T1a[2] = {0, 1}, T0a[2] = {-1, 0};
    static constexpr int T1b[2] = {1, 2}, T0b[2] = {0, 1};
    const short* wl = wr + OFFL0 + 16384;
    f32x4 a[2];
    conv_sp<2, 2, 2, 128>(sm, OFF_H1, wl + 4096, wl, b1s + (r * 7 + 1) * 64,
                          half ? T1b : T1a, half ? T0b : T0a, lane, ct, a);
    RELU_ALL(a, 2)
    store_sp<2>(sm, OFF_Y, half ? 1 : 0, lane, ct, a);
  }
  __syncthreads();
  // ---- L2b: H2 at t={1,9} ----
  {
    static constexpr int T1a[1] = {0}, T0a[1] = {-1}, Ra[1] = {0};
    static constexpr int T1b[1] = {2}, T0b[1] = {1}, Rb[1] = {2};
    const short* wl = wr + OFFL0 + 16384 + 8192;
    f32x4 a[1];
    conv_sp<2, 1, 2, 128>(sm, OFF_Y, wl + 4096, wl, b2s + (r * 7 + 1) * 64,
                          half ? T1b : T1a, half ? T0b : T0a, lane, ct, a);
    resid_sp<1>(sm, OFF_H1, half ? Rb : Ra, lane, ct, a);
    store_sp<1>(sm, OFF_H2, half ? 1 : 0, lane, ct, a);
  }
  __syncthreads();
  // ---- L3a (d=8): Y at t={1,9} ----
  {
    static constexpr int T1a[1] = {0}, T0a[1] = {-1};
    static constexpr int T1b[1] = {1}, T0b[1] = {0};
    const short* wl = wr + OFFL0 + 32768;
    f32x4 a[1];
    conv_sp<2, 1, 2, 128>(sm, OFF_H2, wl + 4096, wl, b1s + (r * 7 + 2) * 64,
                          half ? T1b : T1a, half ? T0b : T0a, lane, ct, a);
    RELU_ALL(a, 1)
    store_sp<1>(sm, OFF_Y, half ? 1 : 0, lane, ct, a);
  }
  __syncthreads();
  // ---- L3b: H3 at t={9} (dup across halves, identical bytes) ----
  {
    static constexpr int T1c[1] = {1}, T0c[1] = {0}, Rc[1] = {1};
    const short* wl = wr + OFFL0 + 32768 + 8192;
    f32x4 a[1];
    conv_sp<2, 1, 2, 128>(sm, OFF_Y, wl + 4096, wl, b2s + (r * 7 + 2) * 64,
                          T1c, T0c, lane, ct, a);
    resid_sp<1>(sm, OFF_H2, Rc, lane, ct, a);
    store_sp<1>(sm, OFF_H3, 0, lane, ct, a);
  }
  __syncthreads();

  // ---- levels 4..7: wave 0 only, barrier-free (wave-local LDS ordering) ----
  if (wave != 0) return;

  f32x4 hfin[4];
  static constexpr int TA[1] = {0};
#pragma unroll 1
  for (int li = 0; li < 4; ++li) {
    const short* base = wr + OFFL0 + (3 + li) * 16384;
    const int prevOff = OFF_H3 + li * 2048;
#pragma unroll
    for (int c2 = 0; c2 < 4; ++c2) {
      f32x4 a[1];
      conv_sp<2, 1, 1, 128>(sm, prevOff, base + 4096, base + 4096,
                            b1s + (r * 7 + 3 + li) * 64, TA, TA, lane, c2, a);
      RELU_ALL(a, 1)
      store_sp<1>(sm, OFF_Y, 0, lane, c2, a);
    }
    __builtin_amdgcn_s_waitcnt(0);
    __builtin_amdgcn_sched_barrier(0);
#pragma unroll
    for (int c2 = 0; c2 < 4; ++c2) {
      f32x4 a[1];
      conv_sp<2, 1, 1, 128>(sm, OFF_Y, base + 8192 + 4096, base + 8192 + 4096,
                            b2s + (r * 7 + 3 + li) * 64, TA, TA, lane, c2, a);
      resid_sp<1>(sm, prevOff, TA, lane, c2, a);
      if (li < 3) store_sp<1>(sm, prevOff + 2048, 0, lane, c2, a);
      hfin[c2] = a[0];
    }
    __builtin_amdgcn_s_waitcnt(0);
    __builtin_amdgcn_sched_barrier(0);
  }

  // ---- epilogue: mask + reduce over 16 seqs, atomic-store P ----
  float mk = mkv[lane & 15];
#pragma unroll
  for (int c2 = 0; c2 < 4; ++c2) {
    float s0 = hfin[c2][0] * mk, s1 = hfin[c2][1] * mk;
    float s2 = hfin[c2][2] * mk, s3 = hfin[c2][3] * mk;
#pragma unroll
    for (int m2 = 1; m2 <= 8; m2 <<= 1) {
      s0 += __shfl_xor(s0, m2);
      s1 += __shfl_xor(s1, m2);
      s2 += __shfl_xor(s2, m2);
      s3 += __shfl_xor(s3, m2);
    }
    if ((lane & 15) == 0) {
      int base = ((r * Bb + b) * 4 + chunk) * 64 + c2 * 16 + (lane >> 4) * 4;
      __hip_atomic_store(&P[base + 0], s0, __ATOMIC_RELAXED, __HIP_MEMORY_SCOPE_AGENT);
      __hip_atomic_store(&P[base + 1], s1, __ATOMIC_RELAXED, __HIP_MEMORY_SCOPE_AGENT);
      __hip_atomic_store(&P[base + 2], s2, __ATOMIC_RELAXED, __HIP_MEMORY_SCOPE_AGENT);
      __hip_atomic_store(&P[base + 3], s3, __ATOMIC_RELAXED, __HIP_MEMORY_SCOPE_AGENT);
    }
  }
  __threadfence();
  finalize(b, P, rel_w, out, cnt, sm, tid);
}

// ---------------------------------------------------------------------------
extern "C" void kernel_launch(void* const* d_in, const int* in_sizes, int n_in,
                              void* d_out, int out_size, void* d_ws, size_t ws_size,
                              hipStream_t stream) {
  const float* emb    = (const float*)d_in[0];
  const float* w1_0   = (const float*)d_in[1];
  const float* b1_0   = (const float*)d_in[2];
  const float* w2_0   = (const float*)d_in[3];
  const float* b2_0   = (const float*)d_in[4];
  const float* down_w = (const float*)d_in[5];
  const float* down_b = (const float*)d_in[6];
  const float* w1s    = (const float*)d_in[7];
  const float* b1s    = (const float*)d_in[8];
  const float* w2s    = (const float*)d_in[9];
  const float* b2s    = (const float*)d_in[10];
  const float* rel_w  = (const float*)d_in[11];
  const int* align_   = (const int*)d_in[12];
  const int* nidx     = (const int*)d_in[13];
  const int* nmask    = (const int*)d_in[14];

  float* P   = (float*)d_ws;                      // 65536 f32 = 256 KB
  int*   cnt = (int*)((char*)d_ws + 262144);      // 64 int
  short* Wf  = (short*)((char*)d_ws + 524288);    // 589824 bf16 = 1.15 MB

  prep_kernel<<<768, 256, 0, stream>>>(w1_0, w2_0, down_w, w1s, w2s, Wf, P, cnt);
  tcn_mfma<<<1024, 512, 0, stream>>>(emb, align_, nidx, nmask, b1_0, b2_0, down_b,
                                     b1s, b2s, Wf, P, cnt, rel_w, (float*)d_out);
}

// Round 9
// 76.646 us; speedup vs baseline: 1.1690x; 1.1690x over previous
//
#include <hip/hip_runtime.h>
#include <hip/hip_bf16.h>
#include <stdint.h>

constexpr int NUM_NODES = 120000;
constexpr int Tn = 10;
constexpr int Bb = 64, Rr = 4, Nn = 64, Ii = 64;
constexpr int RSTR  = 147456;   // per-relation Wf stride (bf16 elems)
constexpr int OFF0  = 0;        // L0 w1   [tap2][ct4][ks4][lane64][8]
constexpr int OFF1  = 16384;    // L0 down [ct4][ks4][lane64][8]
constexpr int OFF2  = 24576;    // L0 w2   [tap2][ct4][ks2][lane64][8]
constexpr int OFFL0 = 32768;    // levels  14 x [tap2][ct4][ks2][lane64][8]

// LDS byte offsets. X (10 slots x 32 cols x 256B) dead after p2; H-chain aliases.
constexpr int OFF_X  = 0;        // 81920
constexpr int OFF_H0 = 0;        // 5 slots * 4096 = 20480
constexpr int OFF_H1 = 20480;    // 3 * 4096
constexpr int OFF_H2 = 32768;    // 2 * 4096
constexpr int OFF_H3 = 40960;    // H3..H6 at +4096 each (ends 57344)
constexpr int OFF_Y  = 81920;    // 10 slots * 4096 = 40960
constexpr int ZOFF   = 122880;   // 256B zero block
constexpr int POFF   = 123136;   // part[2][2][32] f32 = 512B
constexpr int SMEMB  = 123648;

typedef __attribute__((ext_vector_type(8))) short bf16x8;
typedef __attribute__((ext_vector_type(4))) float f32x4;
typedef __attribute__((ext_vector_type(4))) short s16x4;

__device__ __forceinline__ short f2bf(float f) {
  __hip_bfloat16 h = __float2bfloat16(f);
  return *reinterpret_cast<short*>(&h);
}
__device__ __forceinline__ float bf2f(short s) {
  union { unsigned int u; float f; } x;
  x.u = ((unsigned int)(unsigned short)s) << 16;
  return x.f;
}

// ---------------------------------------------------------------------------
// Bake weights into per-lane MFMA A-fragments (bf16). (verified rounds 3-8)
// ---------------------------------------------------------------------------
extern "C" __global__ void prep_kernel(const float* __restrict__ w1_0,
                                       const float* __restrict__ w2_0,
                                       const float* __restrict__ down_w,
                                       const float* __restrict__ w1s,
                                       const float* __restrict__ w2s,
                                       short* __restrict__ Wf) {
  int i0 = blockIdx.x * blockDim.x + threadIdx.x;
  int stride = gridDim.x * blockDim.x;
  for (int e = i0; e < Rr * RSTR; e += stride) {
    int r = e / RSTR, q = e - r * RSTR;
    float v;
    if (q < 16384) {
      int j = q & 7, lane = (q >> 3) & 63, ks = (q >> 9) & 3, ct = (q >> 11) & 3, tap = (q >> 13) & 1;
      int cout = ct * 16 + (lane & 15), cin = ks * 32 + (lane >> 4) * 8 + j;
      v = w1_0[((r * 64 + cout) * 128 + cin) * 2 + tap];
    } else if (q < 24576) {
      int q2 = q - 16384;
      int j = q2 & 7, lane = (q2 >> 3) & 63, ks = (q2 >> 9) & 3, ct = (q2 >> 11) & 3;
      int cout = ct * 16 + (lane & 15), cin = ks * 32 + (lane >> 4) * 8 + j;
      v = down_w[(r * 64 + cout) * 128 + cin];
    } else if (q < 32768) {
      int q2 = q - 24576;
      int j = q2 & 7, lane = (q2 >> 3) & 63, ks = (q2 >> 9) & 1, ct = (q2 >> 10) & 3, tap = (q2 >> 12) & 1;
      int cout = ct * 16 + (lane & 15), cin = ks * 32 + (lane >> 4) * 8 + j;
      v = w2_0[((r * 64 + cout) * 64 + cin) * 2 + tap];
    } else {
      int q2 = q - 32768;
      int lc = q2 >> 13;
      int l = lc >> 1, jw = lc & 1;
      int q3 = q2 & 8191;
      int j = q3 & 7, lane = (q3 >> 3) & 63, ks = (q3 >> 9) & 1, ct = (q3 >> 10) & 3, tap = (q3 >> 12) & 1;
      int cout = ct * 16 + (lane & 15), cin = ks * 32 + (lane >> 4) * 8 + j;
      const float* src = jw ? w2s : w1s;
      v = src[(((r * 7 + l) * 64 + cout) * 64 + cin) * 2 + tap];
    }
    Wf[e] = f2bf(v);
  }
}

// ---------------------------------------------------------------------------
// Conv pass: wave = (ct-pair c, seq-half h). col = slot*32 + h*16 + (lane&15).
// Each B-frag read feeds TWO MFMAs (couts 2c*16.. and (2c+1)*16..).
// ---------------------------------------------------------------------------
template <int KSN, int NMT, int NTAP, int ROWB>
__device__ __forceinline__ void conv_sp(const char* __restrict__ sm, int srcOff,
                                        const short* __restrict__ wf1,
                                        const short* __restrict__ wf0,
                                        const float* __restrict__ bias,
                                        const int (&T1)[NMT], const int (&T0)[NMT],
                                        int lane, int c, int h, f32x4 (&acc)[NMT][2]) {
  const int sw = (lane & 7) << 4;
  const int colb = h * 16 + (lane & 15);
  const int krow = (lane >> 4) * 16;
  float bv[2][4];
#pragma unroll
  for (int i = 0; i < 2; ++i)
#pragma unroll
    for (int g = 0; g < 4; ++g) bv[i][g] = bias[(2 * c + i) * 16 + (lane >> 4) * 4 + g];
#pragma unroll
  for (int mt = 0; mt < NMT; ++mt)
#pragma unroll
    for (int i = 0; i < 2; ++i) acc[mt][i] = (f32x4){bv[i][0], bv[i][1], bv[i][2], bv[i][3]};
#pragma unroll
  for (int ks = 0; ks < KSN; ++ks) {
    bf16x8 a1[2], a0[2];
#pragma unroll
    for (int i = 0; i < 2; ++i)
      a1[i] = *(const bf16x8*)(wf1 + (((2 * c + i) * KSN + ks) * 64 + lane) * 8);
    if (NTAP == 2) {
#pragma unroll
      for (int i = 0; i < 2; ++i)
        a0[i] = *(const bf16x8*)(wf0 + (((2 * c + i) * KSN + ks) * 64 + lane) * 8);
    }
#pragma unroll
    for (int mt = 0; mt < NMT; ++mt) {
      int s1 = T1[mt];
      const char* p1 = sm + ((s1 < 0) ? ZOFF : srcOff + (s1 * 32 + colb) * ROWB);
      bf16x8 b1 = *(const bf16x8*)(p1 + ((ks * 64 + krow) ^ sw));
      acc[mt][0] = __builtin_amdgcn_mfma_f32_16x16x32_bf16(a1[0], b1, acc[mt][0], 0, 0, 0);
      acc[mt][1] = __builtin_amdgcn_mfma_f32_16x16x32_bf16(a1[1], b1, acc[mt][1], 0, 0, 0);
      if (NTAP == 2) {
        int s0 = T0[mt];
        const char* p0 = sm + ((s0 < 0) ? ZOFF : srcOff + (s0 * 32 + colb) * ROWB);
        bf16x8 b0 = *(const bf16x8*)(p0 + ((ks * 64 + krow) ^ sw));
        acc[mt][0] = __builtin_amdgcn_mfma_f32_16x16x32_bf16(a0[0], b0, acc[mt][0], 0, 0, 0);
        acc[mt][1] = __builtin_amdgcn_mfma_f32_16x16x32_bf16(a0[1], b0, acc[mt][1], 0, 0, 0);
      }
    }
  }
}

template <int NMT>
__device__ __forceinline__ void store_sp(char* __restrict__ sm, int dstOff, int lane,
                                         int c, int h, const f32x4 (&v)[NMT][2]) {
  const int sw = (lane & 7) << 4;
  const int colb = h * 16 + (lane & 15);
#pragma unroll
  for (int mt = 0; mt < NMT; ++mt)
#pragma unroll
    for (int i = 0; i < 2; ++i) {
      int co = (2 * c + i) * 32 + (lane >> 4) * 8;
      s16x4 p;
#pragma unroll
      for (int g = 0; g < 4; ++g) p[g] = f2bf(v[mt][i][g]);
      *(s16x4*)(sm + dstOff + (mt * 32 + colb) * 128 + (co ^ sw)) = p;
    }
}

#define RELU_ALL(A, N)                                        \
  _Pragma("unroll") for (int _t = 0; _t < N; ++_t)            \
      _Pragma("unroll") for (int _i = 0; _i < 2; ++_i)        \
          _Pragma("unroll") for (int _g = 0; _g < 4; ++_g)    \
              A[_t][_i][_g] = fmaxf(A[_t][_i][_g], 0.f);

template <int NMT>
__device__ __forceinline__ void resid_sp(const char* __restrict__ sm, int prevOff,
                                         const int (&R)[NMT], int lane, int c, int h,
                                         f32x4 (&a)[NMT][2]) {
  const int sw = (lane & 7) << 4;
  const int colb = h * 16 + (lane & 15);
#pragma unroll
  for (int mt = 0; mt < NMT; ++mt)
#pragma unroll
    for (int i = 0; i < 2; ++i) {
      int co = (2 * c + i) * 32 + (lane >> 4) * 8;
      s16x4 q = *(const s16x4*)(sm + prevOff + (R[mt] * 32 + colb) * 128 + (co ^ sw));
#pragma unroll
      for (int g = 0; g < 4; ++g)
        a[mt][i][g] = fmaxf(fmaxf(a[mt][i][g], 0.f) + bf2f(q[g]), 0.f);
    }
}

// ---------------------------------------------------------------------------
// Main: 32 valid seqs/block; 4 waves = (ct-pair c, seq-half h).
// Grid = r(4) x b(64) x chunk(2) = 512 blocks x 256 thr.
// ---------------------------------------------------------------------------
extern "C" __global__ void __launch_bounds__(256, 1)
tcn_mfma(const float* __restrict__ emb, const int* __restrict__ align_,
         const int* __restrict__ nidx, const int* __restrict__ nmask,
         const float* __restrict__ b1_0, const float* __restrict__ b2_0,
         const float* __restrict__ down_b, const float* __restrict__ b1s,
         const float* __restrict__ b2s, const short* __restrict__ Wf,
         float* __restrict__ P) {
  __shared__ char sm[SMEMB];
  __shared__ int rowid[320];
  __shared__ float mkv[32];
  __shared__ int mapg[32];
  __shared__ int totv;

  const int tid = threadIdx.x;
  const int lane = tid & 63, wave = tid >> 6;
  const int c = wave & 1, h = wave >> 1;
  const int blk = blockIdx.x;
  const int r = blk >> 7;
  const int b = (blk >> 1) & 63, chunk = blk & 1;

  // ---- ballot compaction of this (b,r)'s valid neighbors ----
  if (tid < 64) {
    int n = tid;
    int msk = nmask[(b * Rr + r) * Nn + n];
    unsigned long long bal = __ballot(msk != 0);
    if (tid < 32) mapg[tid] = -1;
    if (tid == 0) totv = (int)__popcll(bal);
    int rank = (int)__popcll(bal & ((1ull << n) - 1ull));
    if (msk != 0 && rank >= chunk * 32 && rank < chunk * 32 + 32)
      mapg[rank - chunk * 32] = n;
  }
  if (tid >= 192 && tid < 224) *(uint64_t*)(sm + ZOFF + (tid - 192) * 8) = 0;
  __syncthreads();
  if (chunk * 32 >= totv) {          // inactive block: zero partial, exit
    if (tid < 64) P[((r * Bb + b) * 2 + chunk) * 64 + tid] = 0.f;
    return;
  }

  // col = t*32 + seq
  for (int i2 = tid; i2 < 320; i2 += 256) {
    int t = i2 >> 5, seq = i2 & 31;
    int n2 = mapg[seq];
    int s = -1;
    if (n2 >= 0) {
      int ent = nidx[(b * Rr + r) * Nn + n2];
      s = align_[ent * Tn + t];
    }
    rowid[i2] = (n2 >= 0 && s >= 0) ? s : -1;
    if (t == 0) mkv[seq] = (n2 >= 0) ? 1.0f : 0.0f;
  }
  __syncthreads();

  // gather: 320 cols x 128 d, f32 -> bf16, swizzled LDS write
#pragma unroll
  for (int it = 0; it < 40; ++it) {
    int idx = tid + it * 256;
    int col = idx >> 5, d4 = idx & 31;
    int row = rowid[col];
    int t = col >> 5;
    s16x4 p = {0, 0, 0, 0};
    if (row >= 0) {
      const float4 v = *(const float4*)(emb + ((size_t)t * NUM_NODES + row) * 128 + d4 * 4);
      p[0] = f2bf(v.x); p[1] = f2bf(v.y); p[2] = f2bf(v.z); p[3] = f2bf(v.w);
    }
    *(s16x4*)(sm + OFF_X + col * 256 + ((d4 * 8) ^ ((col & 7) << 4))) = p;
  }
  __syncthreads();

  const short* wr = Wf + r * RSTR;

  // ---- p1: Y0 = relu(conv1_0(X)), 10 slots ----
  {
    static constexpr int T1[10] = {0, 1, 2, 3, 4, 5, 6, 7, 8, 9};
    static constexpr int T0[10] = {-1, 0, 1, 2, 3, 4, 5, 6, 7, 8};
    f32x4 a[10][2];
    conv_sp<4, 10, 2, 256>(sm, OFF_X, wr + OFF0 + 8192, wr + OFF0, b1_0 + r * 64,
                           T1, T0, lane, c, h, a);
    RELU_ALL(a, 10)
    store_sp<10>(sm, OFF_Y, lane, c, h, a);
  }
  // ---- p2: down(X) at odd t, carried in regs ----
  f32x4 accD[5][2];
  {
    static constexpr int TD[5] = {1, 3, 5, 7, 9};
    conv_sp<4, 5, 1, 256>(sm, OFF_X, wr + OFF1, wr + OFF1, down_b + r * 64,
                          TD, TD, lane, c, h, accD);
  }
  __syncthreads();
  // ---- p3: H0 = relu(relu(conv2_0(Y0)) + down), slots t={1,3,5,7,9} ----
  {
    static constexpr int T1[5] = {1, 3, 5, 7, 9}, T0[5] = {0, 2, 4, 6, 8};
    f32x4 a[5][2];
    conv_sp<2, 5, 2, 128>(sm, OFF_Y, wr + OFF2 + 4096, wr + OFF2, b2_0 + r * 64,
                          T1, T0, lane, c, h, a);
#pragma unroll
    for (int mt = 0; mt < 5; ++mt)
#pragma unroll
      for (int i = 0; i < 2; ++i)
#pragma unroll
        for (int g = 0; g < 4; ++g)
          a[mt][i][g] = fmaxf(fmaxf(a[mt][i][g], 0.f) + accD[mt][i][g], 0.f);
    store_sp<5>(sm, OFF_H0, lane, c, h, a);   // X region now dead
  }
  __syncthreads();
  // ---- L1a (d=2): Y at H0 slots {0..4} ----
  {
    static constexpr int T1[5] = {0, 1, 2, 3, 4}, T0[5] = {-1, 0, 1, 2, 3};
    const short* wl = wr + OFFL0;
    f32x4 a[5][2];
    conv_sp<2, 5, 2, 128>(sm, OFF_H0, wl + 4096, wl, b1s + (r * 7 + 0) * 64,
                          T1, T0, lane, c, h, a);
    RELU_ALL(a, 5)
    store_sp<5>(sm, OFF_Y, lane, c, h, a);
  }
  __syncthreads();
  // ---- L1b: H1 at t={1,5,9} ----
  {
    static constexpr int T1[3] = {0, 2, 4}, T0[3] = {-1, 1, 3}, R[3] = {0, 2, 4};
    const short* wl = wr + OFFL0 + 8192;
    f32x4 a[3][2];
    conv_sp<2, 3, 2, 128>(sm, OFF_Y, wl + 4096, wl, b2s + (r * 7 + 0) * 64,
                          T1, T0, lane, c, h, a);
    resid_sp<3>(sm, OFF_H0, R, lane, c, h, a);
    store_sp<3>(sm, OFF_H1, lane, c, h, a);
  }
  __syncthreads();
  // ---- L2a (d=4): Y at t={1,5,9} ----
  {
    static constexpr int T1[3] = {0, 1, 2}, T0[3] = {-1, 0, 1};
    const short* wl = wr + OFFL0 + 16384;
    f32x4 a[3][2];
    conv_sp<2, 3, 2, 128>(sm, OFF_H1, wl + 4096, wl, b1s + (r * 7 + 1) * 64,
                          T1, T0, lane, c, h, a);
    RELU_ALL(a, 3)
    store_sp<3>(sm, OFF_Y, lane, c, h, a);
  }
  __syncthreads();
  // ---- L2b: H2 at t={1,9} ----
  {
    static constexpr int T1[2] = {0, 2}, T0[2] = {-1, 1}, R[2] = {0, 2};
    const short* wl = wr + OFFL0 + 16384 + 8192;
    f32x4 a[2][2];
    conv_sp<2, 2, 2, 128>(sm, OFF_Y, wl + 4096, wl, b2s + (r * 7 + 1) * 64,
                          T1, T0, lane, c, h, a);
    resid_sp<2>(sm, OFF_H1, R, lane, c, h, a);
    store_sp<2>(sm, OFF_H2, lane, c, h, a);
  }
  __syncthreads();
  // ---- L3a (d=8): Y at t={1,9} ----
  {
    static constexpr int T1[2] = {0, 1}, T0[2] = {-1, 0};
    const short* wl = wr + OFFL0 + 32768;
    f32x4 a[2][2];
    conv_sp<2, 2, 2, 128>(sm, OFF_H2, wl + 4096, wl, b1s + (r * 7 + 2) * 64,
                          T1, T0, lane, c, h, a);
    RELU_ALL(a, 2)
    store_sp<2>(sm, OFF_Y, lane, c, h, a);
  }
  __syncthreads();
  // ---- L3b: H3 at t={9} ----
  {
    static constexpr int T1[1] = {1}, T0[1] = {0}, R[1] = {1};
    const short* wl = wr + OFFL0 + 32768 + 8192;
    f32x4 a[1][2];
    conv_sp<2, 1, 2, 128>(sm, OFF_Y, wl + 4096, wl, b2s + (r * 7 + 2) * 64,
                          T1, T0, lane, c, h, a);
    resid_sp<1>(sm, OFF_H2, R, lane, c, h, a);
    store_sp<1>(sm, OFF_H3, lane, c, h, a);
  }
  __syncthreads();

  // ---- levels 4..7 (d>=16, single tap, single slot t=9) ----
  f32x4 hfin[1][2];
  static constexpr int TA[1] = {0};
#pragma unroll 1
  for (int li = 0; li < 4; ++li) {
    const short* base = wr + OFFL0 + (3 + li) * 16384;
    const int prevOff = OFF_H3 + li * 4096;
    {
      f32x4 a[1][2];
      conv_sp<2, 1, 1, 128>(sm, prevOff, base + 4096, base + 4096,
                            b1s + (r * 7 + 3 + li) * 64, TA, TA, lane, c, h, a);
      RELU_ALL(a, 1)
      store_sp<1>(sm, OFF_Y, lane, c, h, a);
    }
    __syncthreads();
    {
      f32x4 a[1][2];
      conv_sp<2, 1, 1, 128>(sm, OFF_Y, base + 8192 + 4096, base + 8192 + 4096,
                            b2s + (r * 7 + 3 + li) * 64, TA, TA, lane, c, h, a);
      resid_sp<1>(sm, prevOff, TA, lane, c, h, a);
      if (li < 3) store_sp<1>(sm, prevOff + 4096, lane, c, h, a);
      hfin[0][0] = a[0][0];
      hfin[0][1] = a[0][1];
    }
    __syncthreads();
  }

  // ---- epilogue: mask + reduce 16 seqs in-wave, pair halves via LDS ----
  float mk = mkv[h * 16 + (lane & 15)];
  float* part = (float*)(sm + POFF);
#pragma unroll
  for (int i = 0; i < 2; ++i) {
    float s0 = hfin[0][i][0] * mk, s1 = hfin[0][i][1] * mk;
    float s2 = hfin[0][i][2] * mk, s3 = hfin[0][i][3] * mk;
#pragma unroll
    for (int m2 = 1; m2 <= 8; m2 <<= 1) {
      s0 += __shfl_xor(s0, m2);
      s1 += __shfl_xor(s1, m2);
      s2 += __shfl_xor(s2, m2);
      s3 += __shfl_xor(s3, m2);
    }
    if ((lane & 15) == 0) {
      int cl = i * 16 + (lane >> 4) * 4;   // channel within this c's 32
      part[(c * 2 + h) * 32 + cl + 0] = s0;
      part[(c * 2 + h) * 32 + cl + 1] = s1;
      part[(c * 2 + h) * 32 + cl + 2] = s2;
      part[(c * 2 + h) * 32 + cl + 3] = s3;
    }
  }
  __syncthreads();
  if (tid < 64) {
    int c2 = tid >> 5, cl = tid & 31;
    float val = part[(c2 * 2 + 0) * 32 + cl] + part[(c2 * 2 + 1) * 32 + cl];
    P[((r * Bb + b) * 2 + chunk) * 64 + tid] = val;
  }
}

// ---------------------------------------------------------------------------
// out[b][i] = sum_r sum_c (sum_p P[r][b][p][c]) * rel_w[r][c][i]
// ---------------------------------------------------------------------------
extern "C" __global__ void reduce_kernel(const float* __restrict__ P,
                                         const float* __restrict__ rel_w,
                                         float* __restrict__ out) {
  __shared__ float Sl[Rr * 64];
  int b = blockIdx.x, i = threadIdx.x;
  for (int idx = i; idx < Rr * 64; idx += 64) {
    int rr = idx >> 6, cc = idx & 63;
    float s = 0.f;
    for (int p = 0; p < 2; ++p) s += P[((rr * Bb + b) * 2 + p) * 64 + cc];
    Sl[idx] = s;
  }
  __syncthreads();
  float acc = 0.f;
  for (int rr = 0; rr < Rr; ++rr)
#pragma unroll
    for (int cc = 0; cc < 64; ++cc)
      acc += Sl[rr * 64 + cc] * rel_w[(rr * 64 + cc) * Ii + i];
  out[b * Ii + i] = acc;
}

// ---------------------------------------------------------------------------
extern "C" void kernel_launch(void* const* d_in, const int* in_sizes, int n_in,
                              void* d_out, int out_size, void* d_ws, size_t ws_size,
                              hipStream_t stream) {
  const float* emb    = (const float*)d_in[0];
  const float* w1_0   = (const float*)d_in[1];
  const float* b1_0   = (const float*)d_in[2];
  const float* w2_0   = (const float*)d_in[3];
  const float* b2_0   = (const float*)d_in[4];
  const float* down_w = (const float*)d_in[5];
  const float* down_b = (const float*)d_in[6];
  const float* w1s    = (const float*)d_in[7];
  const float* b1s    = (const float*)d_in[8];
  const float* w2s    = (const float*)d_in[9];
  const float* b2s    = (const float*)d_in[10];
  const float* rel_w  = (const float*)d_in[11];
  const int* align_   = (const int*)d_in[12];
  const int* nidx     = (const int*)d_in[13];
  const int* nmask    = (const int*)d_in[14];

  float* P  = (float*)d_ws;                       // 4*64*2*64 f32 = 128 KB
  short* Wf = (short*)((char*)d_ws + 524288);     // 589824 bf16 = 1.15 MB

  prep_kernel<<<768, 256, 0, stream>>>(w1_0, w2_0, down_w, w1s, w2s, Wf);
  tcn_mfma<<<512, 256, 0, stream>>>(emb, align_, nidx, nmask, b1_0, b2_0, down_b,
                                    b1s, b2s, Wf, P);
  reduce_kernel<<<Bb, 64, 0, stream>>>(P, rel_w, (float*)d_out);
}

// Round 10
// 56.965 us; speedup vs baseline: 1.5729x; 1.3455x over previous
//
#include <hip/hip_runtime.h>
#include <hip/hip_bf16.h>
#include <stdint.h>

constexpr int NUM_NODES = 120000;
constexpr int Tn = 10;
constexpr int Bb = 64, Rr = 4, Nn = 64, Cc = 64, Ii = 64;
constexpr int G = 8;            // sequences per block
constexpr int RSTR  = 147456;   // per-relation Wf stride (bf16 elems)
constexpr int OFF0  = 0;        // L0 w1   [tap2][ct4][ks4][lane64][8]
constexpr int OFF1  = 16384;    // L0 down [ct4][ks4][lane64][8]
constexpr int OFF2  = 24576;    // L0 w2   [tap2][ct4][ks2][lane64][8]
constexpr int OFFL0 = 32768;    // levels  14 x [tap2][ct4][ks2][lane64][8]

// LDS byte offsets (H-chain aliases the dead X region)
constexpr int OFF_X  = 0;       // 80 cols x 256B = 20480
constexpr int OFF_H0 = 0;       // 5 slots x 1024 (valid after level 0)
constexpr int OFF_H1 = 6144;    // 3 slots
constexpr int OFF_H2 = 10240;   // 2 slots
constexpr int OFF_H3 = 12288;   // H3..H6 at +1024 each
constexpr int OFF_Y  = 20480;   // 10 slots x 1024
constexpr int ZOFF   = 30720;   // 256B zero block
constexpr int SMEMB  = 30976;

typedef __attribute__((ext_vector_type(8))) short bf16x8;
typedef __attribute__((ext_vector_type(4))) float f32x4;
typedef __attribute__((ext_vector_type(4))) short s16x4;

__device__ __forceinline__ short f2bf(float f) {
  __hip_bfloat16 h = __float2bfloat16(f);
  return *reinterpret_cast<short*>(&h);
}
__device__ __forceinline__ float bf2f(short s) {
  union { unsigned int u; float f; } x;
  x.u = ((unsigned int)(unsigned short)s) << 16;
  return x.f;
}

// ---------------------------------------------------------------------------
// Bake weights into per-lane MFMA A-fragments (bf16). (verified rounds 3-9)
// ---------------------------------------------------------------------------
extern "C" __global__ void prep_kernel(const float* __restrict__ w1_0,
                                       const float* __restrict__ w2_0,
                                       const float* __restrict__ down_w,
                                       const float* __restrict__ w1s,
                                       const float* __restrict__ w2s,
                                       short* __restrict__ Wf) {
  int i0 = blockIdx.x * blockDim.x + threadIdx.x;
  int stride = gridDim.x * blockDim.x;
  for (int e = i0; e < Rr * RSTR; e += stride) {
    int r = e / RSTR, q = e - r * RSTR;
    float v;
    if (q < 16384) {
      int j = q & 7, lane = (q >> 3) & 63, ks = (q >> 9) & 3, ct = (q >> 11) & 3, tap = (q >> 13) & 1;
      int cout = ct * 16 + (lane & 15), cin = ks * 32 + (lane >> 4) * 8 + j;
      v = w1_0[((r * 64 + cout) * 128 + cin) * 2 + tap];
    } else if (q < 24576) {
      int q2 = q - 16384;
      int j = q2 & 7, lane = (q2 >> 3) & 63, ks = (q2 >> 9) & 3, ct = (q2 >> 11) & 3;
      int cout = ct * 16 + (lane & 15), cin = ks * 32 + (lane >> 4) * 8 + j;
      v = down_w[(r * 64 + cout) * 128 + cin];
    } else if (q < 32768) {
      int q2 = q - 24576;
      int j = q2 & 7, lane = (q2 >> 3) & 63, ks = (q2 >> 9) & 1, ct = (q2 >> 10) & 3, tap = (q2 >> 12) & 1;
      int cout = ct * 16 + (lane & 15), cin = ks * 32 + (lane >> 4) * 8 + j;
      v = w2_0[((r * 64 + cout) * 64 + cin) * 2 + tap];
    } else {
      int q2 = q - 32768;
      int lc = q2 >> 13;
      int l = lc >> 1, jw = lc & 1;
      int q3 = q2 & 8191;
      int j = q3 & 7, lane = (q3 >> 3) & 63, ks = (q3 >> 9) & 1, ct = (q3 >> 10) & 3, tap = (q3 >> 12) & 1;
      int cout = ct * 16 + (lane & 15), cin = ks * 32 + (lane >> 4) * 8 + j;
      const float* src = jw ? w2s : w1s;
      v = src[(((r * 7 + l) * 64 + cout) * 64 + cin) * 2 + tap];
    }
    Wf[e] = f2bf(v);
  }
}

// ---------------------------------------------------------------------------
// Sparse-slot conv pass. Input cols packed slot-major (col = slot*8+seq).
// T1/T0: per-output-slot input-slot maps (-1 => zero row). All static.
// ---------------------------------------------------------------------------
template <int KSN, int NMT, int NTAP, int ROWB>
__device__ __forceinline__ void conv_sp(const char* __restrict__ sm, int srcOff,
                                        const short* __restrict__ wf1,
                                        const short* __restrict__ wf0,
                                        const float* __restrict__ bias,
                                        const int (&T1)[NMT * 2], const int (&T0)[NMT * 2],
                                        int lane, int ct, f32x4 (&acc)[NMT]) {
  const int c16 = (lane >> 4) * 16;
  const int seq = lane & 7;
  const int hi = (lane & 15) >> 3;
  const int sw = seq << 4;
  float bv[4];
#pragma unroll
  for (int g = 0; g < 4; ++g) bv[g] = bias[ct * 16 + (lane >> 4) * 4 + g];
#pragma unroll
  for (int mt = 0; mt < NMT; ++mt) acc[mt] = (f32x4){bv[0], bv[1], bv[2], bv[3]};
  bf16x8 af1[KSN], af0[KSN];
#pragma unroll
  for (int ks = 0; ks < KSN; ++ks)
    af1[ks] = *(const bf16x8*)(wf1 + ((ct * KSN + ks) * 64 + lane) * 8);
  if (NTAP == 2) {
#pragma unroll
    for (int ks = 0; ks < KSN; ++ks)
      af0[ks] = *(const bf16x8*)(wf0 + ((ct * KSN + ks) * 64 + lane) * 8);
  }
#pragma unroll
  for (int mt = 0; mt < NMT; ++mt) {
    int s1 = hi ? T1[2 * mt + 1] : T1[2 * mt];
    const char* p1 = sm + ((s1 < 0) ? ZOFF : srcOff + (s1 * 8 + seq) * ROWB);
#pragma unroll
    for (int ks = 0; ks < KSN; ++ks) {
      bf16x8 b = *(const bf16x8*)(p1 + ((ks * 64 + c16) ^ sw));
      acc[mt] = __builtin_amdgcn_mfma_f32_16x16x32_bf16(af1[ks], b, acc[mt], 0, 0, 0);
    }
    if (NTAP == 2) {
      int s0 = hi ? T0[2 * mt + 1] : T0[2 * mt];
      const char* p0 = sm + ((s0 < 0) ? ZOFF : srcOff + (s0 * 8 + seq) * ROWB);
#pragma unroll
      for (int ks = 0; ks < KSN; ++ks) {
        bf16x8 b = *(const bf16x8*)(p0 + ((ks * 64 + c16) ^ sw));
        acc[mt] = __builtin_amdgcn_mfma_f32_16x16x32_bf16(af0[ks], b, acc[mt], 0, 0, 0);
      }
    }
  }
}

template <int NMT>
__device__ __forceinline__ void store_sp(char* __restrict__ sm, int dstOff, int lane,
                                         int ct, const f32x4 (&v)[NMT]) {
  const int co = ct * 32 + (lane >> 4) * 8;
#pragma unroll
  for (int mt = 0; mt < NMT; ++mt) {
    int oc = 16 * mt + (lane & 15);
    s16x4 p;
#pragma unroll
    for (int g = 0; g < 4; ++g) p[g] = f2bf(v[mt][g]);
    *(s16x4*)(sm + dstOff + oc * 128 + (co ^ ((oc & 7) << 4))) = p;
  }
}

#define RELU_ALL(A, N)                                        \
  _Pragma("unroll") for (int _t = 0; _t < N; ++_t)            \
      _Pragma("unroll") for (int _g = 0; _g < 4; ++_g)        \
          A[_t][_g] = fmaxf(A[_t][_g], 0.f);

// residual: h = relu(relu(acc) + H_prev(bf16 from LDS))
template <int NMT>
__device__ __forceinline__ void resid_sp(const char* __restrict__ sm, int prevOff,
                                         const int (&R)[NMT * 2], int lane, int ct,
                                         f32x4 (&a)[NMT]) {
  const int co = ct * 32 + (lane >> 4) * 8;
  const int seq = lane & 7;
  const int hi = (lane & 15) >> 3;
  const int sw = seq << 4;
#pragma unroll
  for (int mt = 0; mt < NMT; ++mt) {
    int rs = hi ? R[2 * mt + 1] : R[2 * mt];
    const char* p = sm + ((rs < 0) ? ZOFF : prevOff + (rs * 8 + seq) * 128);
    s16x4 q = *(const s16x4*)(p + (co ^ sw));
#pragma unroll
    for (int g = 0; g < 4; ++g)
      a[mt][g] = fmaxf(fmaxf(a[mt][g], 0.f) + bf2f(q[g]), 0.f);
  }
}

// ---------------------------------------------------------------------------
// Main: gather + temporally-sparse TCN (44 cols/seq instead of 150).
// Block = 256 thr = 4 waves (wave = cout-tile of 16), 8 valid sequences.
// ---------------------------------------------------------------------------
extern "C" __global__ void __launch_bounds__(256, 4)
tcn_mfma(const float* __restrict__ emb, const int* __restrict__ align_,
         const int* __restrict__ nidx, const int* __restrict__ nmask,
         const float* __restrict__ b1_0, const float* __restrict__ b2_0,
         const float* __restrict__ down_b, const float* __restrict__ b1s,
         const float* __restrict__ b2s, const short* __restrict__ Wf,
         float* __restrict__ P) {
  __shared__ char sm[SMEMB];
  __shared__ int rowid[80];
  __shared__ float mkv[G];
  __shared__ int mapg[G];
  __shared__ int totv;

  const int tid = threadIdx.x;
  const int lane = tid & 63, ct = tid >> 6;
  const int blk = blockIdx.x;
  const int r = blk >> 9;
  const int blkr = blk & 511;
  const int b = blkr >> 3, chunk = blkr & 7;

  // ---- ballot compaction of this (b,r)'s valid neighbors ----
  if (tid < 64) {
    int n = tid;
    int msk = nmask[(b * Rr + r) * Nn + n];
    unsigned long long bal = __ballot(msk != 0);
    if (tid < G) mapg[tid] = -1;
    if (tid == 0) totv = (int)__popcll(bal);
    int rank = (int)__popcll(bal & ((1ull << n) - 1ull));
    if (msk != 0 && rank >= chunk * G && rank < chunk * G + G)
      mapg[rank - chunk * G] = n;
  }
  if (tid >= 192 && tid < 224) *(uint64_t*)(sm + ZOFF + (tid - 192) * 8) = 0;
  __syncthreads();
  if (chunk * G >= totv) {           // inactive block: zero partial, exit
    if (tid < 64) P[((r * Bb + b) * 8 + chunk) * 64 + tid] = 0.f;
    return;
  }

  // col = t*8 + seq  (slot-major packing)
  if (tid < 80) {
    int t = tid >> 3, seq = tid & 7;
    int n2 = mapg[seq];
    int s = -1;
    if (n2 >= 0) {
      int ent = nidx[(b * Rr + r) * Nn + n2];
      s = align_[ent * Tn + t];
    }
    rowid[tid] = (n2 >= 0 && s >= 0) ? s : -1;
    if (t == 0) mkv[seq] = (n2 >= 0) ? 1.0f : 0.0f;
  }
  __syncthreads();

  // gather: 80 cols x 128 d, f32 -> bf16, b128 swizzled LDS writes
  // (16 threads/col, 8 d-elems/thread: halves LDS write instruction count)
#pragma unroll
  for (int it = 0; it < 5; ++it) {
    int idx = tid + it * 256;
    int col = idx >> 4, d8 = idx & 15;
    int row = rowid[col];
    int t = col >> 3;
    bf16x8 p = {0, 0, 0, 0, 0, 0, 0, 0};
    if (row >= 0) {
      const float* src = emb + ((size_t)t * NUM_NODES + row) * 128 + d8 * 8;
      const float4 v0 = *(const float4*)(src);
      const float4 v1 = *(const float4*)(src + 4);
      p[0] = f2bf(v0.x); p[1] = f2bf(v0.y); p[2] = f2bf(v0.z); p[3] = f2bf(v0.w);
      p[4] = f2bf(v1.x); p[5] = f2bf(v1.y); p[6] = f2bf(v1.z); p[7] = f2bf(v1.w);
    }
    *(bf16x8*)(sm + OFF_X + col * 256 + ((d8 * 16) ^ ((col & 7) << 4))) = p;
  }
  __syncthreads();

  const short* wr = Wf + r * RSTR;

  // ---- pass1: Y0 = relu(conv1_0(X)), all t ----
  {
    constexpr int T1[10] = {0, 1, 2, 3, 4, 5, 6, 7, 8, 9};
    constexpr int T0[10] = {-1, 0, 1, 2, 3, 4, 5, 6, 7, 8};
    f32x4 a[5];
    conv_sp<4, 5, 2, 256>(sm, OFF_X, wr + OFF0 + 8192, wr + OFF0, b1_0 + r * 64,
                          T1, T0, lane, ct, a);
    RELU_ALL(a, 5)
    store_sp<5>(sm, OFF_Y, lane, ct, a);
  }
  // ---- pass2: down(X) at odd t, carried in regs ----
  f32x4 accD[3];
  {
    constexpr int TD[6] = {1, 3, 5, 7, 9, 9};
    conv_sp<4, 3, 1, 256>(sm, OFF_X, wr + OFF1, wr + OFF1, down_b + r * 64,
                          TD, TD, lane, ct, accD);
  }
  __syncthreads();
  // ---- pass3: H0 = relu(relu(conv2_0(Y0)) + down) at odd t ----
  {
    constexpr int T1[6] = {1, 3, 5, 7, 9, 9};
    constexpr int T0[6] = {0, 2, 4, 6, 8, 8};
    f32x4 a[3];
    conv_sp<2, 3, 2, 128>(sm, OFF_Y, wr + OFF2 + 4096, wr + OFF2, b2_0 + r * 64,
                          T1, T0, lane, ct, a);
#pragma unroll
    for (int mt = 0; mt < 3; ++mt)
#pragma unroll
      for (int g = 0; g < 4; ++g)
        a[mt][g] = fmaxf(fmaxf(a[mt][g], 0.f) + accD[mt][g], 0.f);
    store_sp<3>(sm, OFF_H0, lane, ct, a);
  }
  __syncthreads();
  // ---- level 1 (d=2): Y1 at H0-slots; H1 at [1,5,9] ----
  {
    constexpr int T1[6] = {0, 1, 2, 3, 4, 4};
    constexpr int T0[6] = {-1, 0, 1, 2, 3, 3};
    f32x4 a[3];
    const short* wb = wr + OFFL0;
    conv_sp<2, 3, 2, 128>(sm, OFF_H0, wb + 4096, wb, b1s + (r * 7 + 0) * 64,
                          T1, T0, lane, ct, a);
    RELU_ALL(a, 3)
    store_sp<3>(sm, OFF_Y, lane, ct, a);
  }
  __syncthreads();
  {
    constexpr int T1[4] = {0, 2, 4, 4};
    constexpr int T0[4] = {-1, 1, 3, 3};
    constexpr int R[4] = {0, 2, 4, 4};
    f32x4 a[2];
    const short* wb = wr + OFFL0 + 8192;
    conv_sp<2, 2, 2, 128>(sm, OFF_Y, wb + 4096, wb, b2s + (r * 7 + 0) * 64,
                          T1, T0, lane, ct, a);
    resid_sp<2>(sm, OFF_H0, R, lane, ct, a);
    store_sp<2>(sm, OFF_H1, lane, ct, a);
  }
  __syncthreads();
  // ---- level 2 (d=4): Y2 at [1,5,9]; H2 at [1,9] ----
  {
    constexpr int T1[4] = {0, 1, 2, 2};
    constexpr int T0[4] = {-1, 0, 1, 1};
    f32x4 a[2];
    const short* wb = wr + OFFL0 + 16384;
    conv_sp<2, 2, 2, 128>(sm, OFF_H1, wb + 4096, wb, b1s + (r * 7 + 1) * 64,
                          T1, T0, lane, ct, a);
    RELU_ALL(a, 2)
    store_sp<2>(sm, OFF_Y, lane, ct, a);
  }
  __syncthreads();
  {
    constexpr int T1[2] = {0, 2};
    constexpr int T0[2] = {-1, 1};
    constexpr int R[2] = {0, 2};
    f32x4 a[1];
    const short* wb = wr + OFFL0 + 16384 + 8192;
    conv_sp<2, 1, 2, 128>(sm, OFF_Y, wb + 4096, wb, b2s + (r * 7 + 1) * 64,
                          T1, T0, lane, ct, a);
    resid_sp<1>(sm, OFF_H1, R, lane, ct, a);
    store_sp<1>(sm, OFF_H2, lane, ct, a);
  }
  __syncthreads();
  // ---- level 3 (d=8): Y3 at [1,9]; H3 at [9] ----
  {
    constexpr int T1[2] = {0, 1};
    constexpr int T0[2] = {-1, 0};
    f32x4 a[1];
    const short* wb = wr + OFFL0 + 32768;
    conv_sp<2, 1, 2, 128>(sm, OFF_H2, wb + 4096, wb, b1s + (r * 7 + 2) * 64,
                          T1, T0, lane, ct, a);
    RELU_ALL(a, 1)
    store_sp<1>(sm, OFF_Y, lane, ct, a);
  }
  __syncthreads();
  {
    constexpr int T1[2] = {1, 1};
    constexpr int T0[2] = {0, 0};
    constexpr int R[2] = {1, 1};
    f32x4 a[1];
    const short* wb = wr + OFFL0 + 32768 + 8192;
    conv_sp<2, 1, 2, 128>(sm, OFF_Y, wb + 4096, wb, b2s + (r * 7 + 2) * 64,
                          T1, T0, lane, ct, a);
    resid_sp<1>(sm, OFF_H2, R, lane, ct, a);
    store_sp<1>(sm, OFF_H3, lane, ct, a);
  }
  __syncthreads();

  // ---- levels 4..7 (d>=16, single tap, single slot t=9) ----
  f32x4 hfin[1];
  static constexpr int TA[2] = {0, 0};
#pragma unroll 1
  for (int li = 0; li < 4; ++li) {
    const short* base = wr + OFFL0 + (3 + li) * 16384;
    const int prevOff = OFF_H3 + li * 1024;
    {
      f32x4 a[1];
      conv_sp<2, 1, 1, 128>(sm, prevOff, base + 4096, base + 4096,
                            b1s + (r * 7 + 3 + li) * 64, TA, TA, lane, ct, a);
      RELU_ALL(a, 1)
      store_sp<1>(sm, OFF_Y, lane, ct, a);
    }
    __syncthreads();
    {
      f32x4 a[1];
      conv_sp<2, 1, 1, 128>(sm, OFF_Y, base + 8192 + 4096, base + 8192 + 4096,
                            b2s + (r * 7 + 3 + li) * 64, TA, TA, lane, ct, a);
      resid_sp<1>(sm, prevOff, TA, lane, ct, a);
      if (li < 3) store_sp<1>(sm, prevOff + 1024, lane, ct, a);
      hfin[0] = a[0];
    }
    __syncthreads();
  }

  // ---- epilogue: mask + reduce over 8 sequences (lanes 0-7 of each group) ----
  float mk = ((lane & 15) < 8) ? mkv[lane & 7] : 0.f;
  float s0 = hfin[0][0] * mk, s1 = hfin[0][1] * mk, s2 = hfin[0][2] * mk, s3 = hfin[0][3] * mk;
#pragma unroll
  for (int m2 = 1; m2 <= 4; m2 <<= 1) {
    s0 += __shfl_xor(s0, m2);
    s1 += __shfl_xor(s1, m2);
    s2 += __shfl_xor(s2, m2);
    s3 += __shfl_xor(s3, m2);
  }
  if ((lane & 15) == 0) {
    int base = ((r * Bb + b) * 8 + chunk) * 64 + ct * 16 + (lane >> 4) * 4;
    P[base + 0] = s0;
    P[base + 1] = s1;
    P[base + 2] = s2;
    P[base + 3] = s3;
  }
}

// ---------------------------------------------------------------------------
// out[b][i] = sum_r sum_c (sum_p P[r][b][p][c]) * rel_w[r][c][i]
// ---------------------------------------------------------------------------
extern "C" __global__ void reduce_kernel(const float* __restrict__ P,
                                         const float* __restrict__ rel_w,
                                         float* __restrict__ out) {
  __shared__ float Sl[Rr * Cc];
  int b = blockIdx.x, i = threadIdx.x;
  for (int idx = i; idx < Rr * Cc; idx += 64) {
    int rr = idx >> 6, cc = idx & 63;
    float s = 0.f;
    for (int p = 0; p < 8; ++p) s += P[((rr * Bb + b) * 8 + p) * 64 + cc];
    Sl[idx] = s;
  }
  __syncthreads();
  float acc = 0.f;
  for (int r = 0; r < Rr; ++r)
#pragma unroll
    for (int cc = 0; cc < 64; ++cc)
      acc += Sl[r * Cc + cc] * rel_w[(r * Cc + cc) * Ii + i];
  out[b * Ii + i] = acc;
}

// ---------------------------------------------------------------------------
extern "C" void kernel_launch(void* const* d_in, const int* in_sizes, int n_in,
                              void* d_out, int out_size, void* d_ws, size_t ws_size,
                              hipStream_t stream) {
  const float* emb    = (const float*)d_in[0];
  const float* w1_0   = (const float*)d_in[1];
  const float* b1_0   = (const float*)d_in[2];
  const float* w2_0   = (const float*)d_in[3];
  const float* b2_0   = (const float*)d_in[4];
  const float* down_w = (const float*)d_in[5];
  const float* down_b = (const float*)d_in[6];
  const float* w1s    = (const float*)d_in[7];
  const float* b1s    = (const float*)d_in[8];
  const float* w2s    = (const float*)d_in[9];
  const float* b2s    = (const float*)d_in[10];
  const float* rel_w  = (const float*)d_in[11];
  const int* align_   = (const int*)d_in[12];
  const int* nidx     = (const int*)d_in[13];
  const int* nmask    = (const int*)d_in[14];

  float* P  = (float*)d_ws;                       // 4*64*8*64 f32 = 512 KB
  short* Wf = (short*)((char*)d_ws + 524288);     // 589824 bf16 = 1.15 MB

  prep_kernel<<<768, 256, 0, stream>>>(w1_0, w2_0, down_w, w1s, w2s, Wf);
  tcn_mfma<<<2048, 256, 0, stream>>>(emb, align_, nidx, nmask, b1_0, b2_0, down_b,
                                     b1s, b2s, Wf, P);
  reduce_kernel<<<Bb, Cc, 0, stream>>>(P, rel_w, (float*)d_out);
}